// Round 1
// 529.247 us; speedup vs baseline: 1.0024x; 1.0024x over previous
//
#include <hip/hip_runtime.h>
#include <hip/hip_bf16.h>
#include <stdint.h>

// out = A_sparse @ (X @ W) + b
// Phase 1: CSR build (hist -> scan -> permute into interleaved int2 pairs).
// Phase 2: W -> bf16 transposed (Wt[n][k]).
// Phase 3: XWb = X @ W via MFMA 16x16x32 bf16; fp32->bf16 conversion of X fused
//          into the A-staging (no separate convert kernel, no Xb buffer).
// Phase 4: per-node wave gathers bf16 XWb[col] rows (8B/lane), unroll-4 for MLP,
//          fp32 accum, +bias, fp32 out.

#define D 256  // D_IN == D_OUT == 256

typedef __attribute__((ext_vector_type(8))) short bf16x8;
typedef __attribute__((ext_vector_type(4))) float f32x4;

__device__ __forceinline__ unsigned short f32_to_bf16(float f) {
    union { float f; unsigned int u; } x; x.f = f;
    unsigned int u = x.u;
    u += 0x7fffu + ((u >> 16) & 1u);   // round-to-nearest-even
    return (unsigned short)(u >> 16);
}
__device__ __forceinline__ float bf16_to_f32(unsigned short h) {
    union { unsigned int u; float f; } x; x.u = ((unsigned int)h) << 16;
    return x.f;
}

// ---------------- CSR build ----------------

__global__ void hist_kernel(const int* __restrict__ row, int* __restrict__ counts, int E) {
    int e = blockIdx.x * 256 + threadIdx.x;
    if (e < E) atomicAdd(&counts[row[e]], 1);
}

__global__ void block_sums_kernel(const int* __restrict__ counts, int* __restrict__ partials, int M) {
    __shared__ int s[256];
    int i = blockIdx.x * 256 + threadIdx.x;
    s[threadIdx.x] = (i < M) ? counts[i] : 0;
    __syncthreads();
    for (int off = 128; off > 0; off >>= 1) {
        if (threadIdx.x < off) s[threadIdx.x] += s[threadIdx.x + off];
        __syncthreads();
    }
    if (threadIdx.x == 0) partials[blockIdx.x] = s[0];
}

__global__ void scan_partials_kernel(int* __restrict__ partials, int NB) {
    __shared__ int buf[256];
    __shared__ int carry_s;
    if (threadIdx.x == 0) carry_s = 0;
    __syncthreads();
    for (int base = 0; base < NB; base += 256) {
        int i = base + threadIdx.x;
        int v = (i < NB) ? partials[i] : 0;
        buf[threadIdx.x] = v;
        __syncthreads();
        #pragma unroll
        for (int off = 1; off < 256; off <<= 1) {
            int t = (threadIdx.x >= off) ? buf[threadIdx.x - off] : 0;
            __syncthreads();
            buf[threadIdx.x] += t;
            __syncthreads();
        }
        int incl = buf[threadIdx.x];
        if (i < NB) partials[i] = carry_s + incl - v;  // exclusive
        __syncthreads();
        if (threadIdx.x == 0) carry_s += buf[255];
        __syncthreads();
    }
}

__global__ void scan_local_kernel(const int* __restrict__ counts, const int* __restrict__ partials,
                                  int* __restrict__ offsets, int* __restrict__ cursor, int M) {
    __shared__ int buf[256];
    int i = blockIdx.x * 256 + threadIdx.x;
    int v = (i < M) ? counts[i] : 0;
    buf[threadIdx.x] = v;
    __syncthreads();
    #pragma unroll
    for (int off = 1; off < 256; off <<= 1) {
        int t = (threadIdx.x >= off) ? buf[threadIdx.x - off] : 0;
        __syncthreads();
        buf[threadIdx.x] += t;
        __syncthreads();
    }
    int excl = partials[blockIdx.x] + buf[threadIdx.x] - v;
    if (i < M) { offsets[i] = excl; cursor[i] = excl; }
    if (i == M - 1) offsets[M] = excl + v;
}

// Scatter (col,val) interleaved as int2: one 8B store per edge instead of two 4B
// stores to two different random cache lines.
__global__ void permute_kernel(const int* __restrict__ row, const int* __restrict__ col,
                               const float* __restrict__ val, int* __restrict__ cursor,
                               int2* __restrict__ spair, int E) {
    int e = blockIdx.x * 256 + threadIdx.x;
    if (e < E) {
        int r = row[e];
        int pos = atomicAdd(&cursor[r], 1);
        spair[pos] = make_int2(col[e], __float_as_int(val[e]));
    }
}

// ---------------- Conversions ----------------

// W (fp32 [k][n]) -> Wt (bf16 [n][k])
__global__ __launch_bounds__(256) void convert_wt_kernel(const float* __restrict__ W,
                                                         unsigned short* __restrict__ Wt) {
    int i = blockIdx.x * 256 + threadIdx.x;   // i = n*256 + k
    int n = i >> 8, k = i & 255;
    Wt[i] = f32_to_bf16(W[k * 256 + n]);
}

// ---------------- MFMA GEMM: XWb = X @ W  (fp32 in -> bf16 staged, bf16 out) ----------------
// BM=128, BN=128, BK=32. 256 threads = 4 waves in 2x2; each wave: 4x4 grid of 16x16 tiles.
// LDS rows padded to 40 bf16 (80B) -> 2-way bank aliasing (free).
// A-staging reads X fp32 directly and rounds to bf16 in registers (fuses convert_x).
// X (100 MB) fits L3, so the grid.y=1 pass's reads hit Infinity Cache on grid.y=0's fill.

__global__ __launch_bounds__(256) void gemm_mfma_kernel(const float* __restrict__ X,
                                                        const unsigned short* __restrict__ Wt,
                                                        unsigned short* __restrict__ XWb, int M) {
    __shared__ unsigned short As[128 * 40];  // [m][k] padded
    __shared__ unsigned short Bs[128 * 40];  // [n][k] padded

    const int tid = threadIdx.x;
    const int wave = tid >> 6, lane = tid & 63;
    const int quad = lane >> 4, r = lane & 15;
    const int wm = (wave & 1) * 64, wn = (wave >> 1) * 64;
    const int m0 = blockIdx.x * 128;
    const int n0 = blockIdx.y * 128;

    const int srow = tid >> 2;        // 0..63, staging row
    const int sseg = tid & 3;         // 16B (8-elem) segment within 32-k row

    f32x4 acc[4][4] = {};

    for (int k0 = 0; k0 < D; k0 += 32) {
        // stage A: 128 rows x 32 k (two halves of 64 rows); fp32 load + bf16 round fused
        #pragma unroll
        for (int h = 0; h < 2; ++h) {
            int row = srow + h * 64;
            int gm = m0 + row;
            ushort4 lo = make_ushort4(0, 0, 0, 0), hi = make_ushort4(0, 0, 0, 0);
            if (gm < M) {
                const float* src = X + (size_t)gm * D + k0 + sseg * 8;
                float4 f0 = *(const float4*)(src);
                float4 f1 = *(const float4*)(src + 4);
                lo.x = f32_to_bf16(f0.x); lo.y = f32_to_bf16(f0.y);
                lo.z = f32_to_bf16(f0.z); lo.w = f32_to_bf16(f0.w);
                hi.x = f32_to_bf16(f1.x); hi.y = f32_to_bf16(f1.y);
                hi.z = f32_to_bf16(f1.z); hi.w = f32_to_bf16(f1.w);
            }
            *(ushort4*)(&As[row * 40 + sseg * 8]) = lo;
            *(ushort4*)(&As[row * 40 + sseg * 8 + 4]) = hi;
        }
        // stage B: 128 n-rows x 32 k from Wt (already bf16)
        #pragma unroll
        for (int h = 0; h < 2; ++h) {
            int row = srow + h * 64;
            uint4 v = *(const uint4*)(Wt + (size_t)(n0 + row) * D + k0 + sseg * 8);
            *(uint4*)(&Bs[row * 40 + sseg * 8]) = v;
        }
        __syncthreads();

        bf16x8 a[4], b[4];
        #pragma unroll
        for (int mt = 0; mt < 4; ++mt)
            a[mt] = *(const bf16x8*)(&As[(wm + mt * 16 + r) * 40 + quad * 8]);
        #pragma unroll
        for (int nt = 0; nt < 4; ++nt)
            b[nt] = *(const bf16x8*)(&Bs[(wn + nt * 16 + r) * 40 + quad * 8]);
        #pragma unroll
        for (int mt = 0; mt < 4; ++mt)
            #pragma unroll
            for (int nt = 0; nt < 4; ++nt)
                acc[mt][nt] = __builtin_amdgcn_mfma_f32_16x16x32_bf16(a[mt], b[nt], acc[mt][nt], 0, 0, 0);
        __syncthreads();
    }

    // epilogue: C[row=quad*4+reg][col=lane&15] per 16x16 tile
    #pragma unroll
    for (int mt = 0; mt < 4; ++mt) {
        #pragma unroll
        for (int reg = 0; reg < 4; ++reg) {
            int gm = m0 + wm + mt * 16 + quad * 4 + reg;
            if (gm < M) {
                #pragma unroll
                for (int nt = 0; nt < 4; ++nt) {
                    int gn = n0 + wn + nt * 16 + r;
                    XWb[(size_t)gm * D + gn] = f32_to_bf16(acc[mt][nt][reg]);
                }
            }
        }
    }
}

// ---------------- Gather: out[node] = bias + sum_e val_e * XWb[col_e] ----------------
// One wave per node; lane owns 4 bf16 dims (8B load per edge).
// Unroll-4: 4 independent pair loads then 4 independent row gathers in flight
// before any FMA -> ~2x memory-level parallelism per wave vs unroll-2.

__global__ __launch_bounds__(256) void gather_kernel(const unsigned short* __restrict__ XWb,
                                                     const int* __restrict__ offsets,
                                                     const int2* __restrict__ spair,
                                                     const float* __restrict__ bias,
                                                     float* __restrict__ out, int M) {
    int node = (int)((blockIdx.x * (size_t)blockDim.x + threadIdx.x) >> 6);
    int lane = threadIdx.x & 63;
    if (node >= M) return;
    int beg = offsets[node], end = offsets[node + 1];
    const unsigned short* base = XWb + lane * 4;
    float4 acc = make_float4(0.f, 0.f, 0.f, 0.f);
    int e = beg;
    for (; e + 3 < end; e += 4) {
        int2 p0 = spair[e];
        int2 p1 = spair[e + 1];
        int2 p2 = spair[e + 2];
        int2 p3 = spair[e + 3];
        ushort4 x0 = *(const ushort4*)(base + (size_t)p0.x * D);
        ushort4 x1 = *(const ushort4*)(base + (size_t)p1.x * D);
        ushort4 x2 = *(const ushort4*)(base + (size_t)p2.x * D);
        ushort4 x3 = *(const ushort4*)(base + (size_t)p3.x * D);
        float v0 = __int_as_float(p0.y), v1 = __int_as_float(p1.y);
        float v2 = __int_as_float(p2.y), v3 = __int_as_float(p3.y);
        acc.x += v0 * bf16_to_f32(x0.x); acc.y += v0 * bf16_to_f32(x0.y);
        acc.z += v0 * bf16_to_f32(x0.z); acc.w += v0 * bf16_to_f32(x0.w);
        acc.x += v1 * bf16_to_f32(x1.x); acc.y += v1 * bf16_to_f32(x1.y);
        acc.z += v1 * bf16_to_f32(x1.z); acc.w += v1 * bf16_to_f32(x1.w);
        acc.x += v2 * bf16_to_f32(x2.x); acc.y += v2 * bf16_to_f32(x2.y);
        acc.z += v2 * bf16_to_f32(x2.z); acc.w += v2 * bf16_to_f32(x2.w);
        acc.x += v3 * bf16_to_f32(x3.x); acc.y += v3 * bf16_to_f32(x3.y);
        acc.z += v3 * bf16_to_f32(x3.z); acc.w += v3 * bf16_to_f32(x3.w);
    }
    for (; e < end; ++e) {
        int2 p = spair[e];
        float v = __int_as_float(p.y);
        ushort4 x = *(const ushort4*)(base + (size_t)p.x * D);
        acc.x += v * bf16_to_f32(x.x); acc.y += v * bf16_to_f32(x.y);
        acc.z += v * bf16_to_f32(x.z); acc.w += v * bf16_to_f32(x.w);
    }
    float4 b = *(const float4*)(bias + lane * 4);
    acc.x += b.x; acc.y += b.y; acc.z += b.z; acc.w += b.w;
    *(float4*)(out + (size_t)node * D + lane * 4) = acc;
}

extern "C" void kernel_launch(void* const* d_in, const int* in_sizes, int n_in,
                              void* d_out, int out_size, void* d_ws, size_t ws_size,
                              hipStream_t stream) {
    const float* X    = (const float*)d_in[0];
    const int*   erow = (const int*)d_in[1];
    const int*   ecol = (const int*)d_in[2];
    const float* eval = (const float*)d_in[3];
    const float* W    = (const float*)d_in[4];
    const float* bias = (const float*)d_in[5];
    float* out = (float*)d_out;

    const int M = in_sizes[0] / D;   // 100000
    const int E = in_sizes[1];       // 1600000
    const int NB = (M + 255) / 256;  // 391

    // workspace carve (~66 MB)
    char* p = (char*)d_ws;
    unsigned short* XWb = (unsigned short*)p; p += (size_t)M * D * sizeof(unsigned short);
    unsigned short* Wt  = (unsigned short*)p; p += (size_t)D * D * sizeof(unsigned short);
    int* counts = (int*)p;      p += (size_t)M * sizeof(int);
    int* offsets = (int*)p;     p += (size_t)(M + 1) * sizeof(int);
    int* cursor = (int*)p;      p += (size_t)M * sizeof(int);
    int* partials = (int*)p;    p += (size_t)NB * sizeof(int);
    p = (char*)(((uintptr_t)p + 15) & ~(uintptr_t)15);
    int2* spair = (int2*)p;     p += (size_t)E * sizeof(int2);

    hipMemsetAsync(counts, 0, (size_t)M * sizeof(int), stream);
    hist_kernel<<<(E + 255) / 256, 256, 0, stream>>>(erow, counts, E);
    block_sums_kernel<<<NB, 256, 0, stream>>>(counts, partials, M);
    scan_partials_kernel<<<1, 256, 0, stream>>>(partials, NB);
    scan_local_kernel<<<NB, 256, 0, stream>>>(counts, partials, offsets, cursor, M);
    permute_kernel<<<(E + 255) / 256, 256, 0, stream>>>(erow, ecol, eval, cursor, spair, E);

    convert_wt_kernel<<<(D * D) / 256, 256, 0, stream>>>(W, Wt);

    dim3 ggrid((M + 127) / 128, D / 128);
    gemm_mfma_kernel<<<ggrid, 256, 0, stream>>>(X, Wt, XWb, M);

    gather_kernel<<<(int)(((size_t)M * 64 + 255) / 256), 256, 0, stream>>>(
        XWb, offsets, spair, bias, out, M);
}

// Round 2
// 469.579 us; speedup vs baseline: 1.1297x; 1.1271x over previous
//
#include <hip/hip_runtime.h>
#include <hip/hip_bf16.h>
#include <stdint.h>

// out = A_sparse @ (X @ W) + b
// Phase 1: CSR build: hist -> scan -> two-phase multisplit:
//          (a) binned_scatter: bucket edges by (row>>8) with per-block LDS hist,
//              block-contiguous runs -> full-line writes from a single XCD.
//          (b) local_sort: one block per 256-node bucket, LDS cursors -> fully
//              CSR-sorted spair; all writes inside the bucket's contiguous region.
// Phase 2: W -> bf16 transposed (Wt[n][k]).
// Phase 3: XWb = X @ W via MFMA 16x16x32 bf16 (fp32->bf16 fused into A-staging).
// Phase 4: per-node wave gathers bf16 XWb[col] rows (8B/lane), unroll-4, fp32 out.

#define D 256  // D_IN == D_OUT == 256

typedef __attribute__((ext_vector_type(8))) short bf16x8;
typedef __attribute__((ext_vector_type(4))) float f32x4;

__device__ __forceinline__ unsigned short f32_to_bf16(float f) {
    union { float f; unsigned int u; } x; x.f = f;
    unsigned int u = x.u;
    u += 0x7fffu + ((u >> 16) & 1u);   // round-to-nearest-even
    return (unsigned short)(u >> 16);
}
__device__ __forceinline__ float bf16_to_f32(unsigned short h) {
    union { unsigned int u; float f; } x; x.u = ((unsigned int)h) << 16;
    return x.f;
}

// ---------------- CSR build ----------------

__global__ void hist_kernel(const int* __restrict__ row, int* __restrict__ counts, int E) {
    int e = blockIdx.x * 256 + threadIdx.x;
    if (e < E) atomicAdd(&counts[row[e]], 1);
}

__global__ void block_sums_kernel(const int* __restrict__ counts, int* __restrict__ partials, int M) {
    __shared__ int s[256];
    int i = blockIdx.x * 256 + threadIdx.x;
    s[threadIdx.x] = (i < M) ? counts[i] : 0;
    __syncthreads();
    for (int off = 128; off > 0; off >>= 1) {
        if (threadIdx.x < off) s[threadIdx.x] += s[threadIdx.x + off];
        __syncthreads();
    }
    if (threadIdx.x == 0) partials[blockIdx.x] = s[0];
}

__global__ void scan_partials_kernel(int* __restrict__ partials, int NB) {
    __shared__ int buf[256];
    __shared__ int carry_s;
    if (threadIdx.x == 0) carry_s = 0;
    __syncthreads();
    for (int base = 0; base < NB; base += 256) {
        int i = base + threadIdx.x;
        int v = (i < NB) ? partials[i] : 0;
        buf[threadIdx.x] = v;
        __syncthreads();
        #pragma unroll
        for (int off = 1; off < 256; off <<= 1) {
            int t = (threadIdx.x >= off) ? buf[threadIdx.x - off] : 0;
            __syncthreads();
            buf[threadIdx.x] += t;
            __syncthreads();
        }
        int incl = buf[threadIdx.x];
        if (i < NB) partials[i] = carry_s + incl - v;  // exclusive
        __syncthreads();
        if (threadIdx.x == 0) carry_s += buf[255];
        __syncthreads();
    }
}

// Also initializes the per-bucket global cursor: bucket b's region starts at
// offsets[b*256], which equals partials[b] (block-exclusive prefix).
__global__ void scan_local_kernel(const int* __restrict__ counts, const int* __restrict__ partials,
                                  int* __restrict__ offsets, int* __restrict__ bcursor, int M) {
    __shared__ int buf[256];
    int i = blockIdx.x * 256 + threadIdx.x;
    int v = (i < M) ? counts[i] : 0;
    buf[threadIdx.x] = v;
    __syncthreads();
    #pragma unroll
    for (int off = 1; off < 256; off <<= 1) {
        int t = (threadIdx.x >= off) ? buf[threadIdx.x - off] : 0;
        __syncthreads();
        buf[threadIdx.x] += t;
        __syncthreads();
    }
    int excl = partials[blockIdx.x] + buf[threadIdx.x] - v;
    if (i < M) offsets[i] = excl;
    if (i == M - 1) offsets[M] = excl + v;
    if (threadIdx.x == 0) bcursor[blockIdx.x] = partials[blockIdx.x];
}

// ---------------- Two-phase multisplit ----------------
// Phase A: bucket edges by row>>8. Each block processes 4096 edges, reserves one
// contiguous run per bucket via a single global atomic, scatters packed pairs
// into its runs. Runs are block-private -> one XCD writes each line -> L2
// accumulates full lines -> ~8x less HBM write traffic than per-edge scatter.

#define EPB 4096          // edges per binned_scatter block
#define NBUCKET_MAX 512   // supports M <= 131072

__global__ __launch_bounds__(256) void binned_scatter_kernel(
        const int* __restrict__ row, const int* __restrict__ col,
        const float* __restrict__ val, int* __restrict__ bcursor,
        int2* __restrict__ bpair, int E) {
    __shared__ int rows_s[EPB];          // 16 KB
    __shared__ int cnt[NBUCKET_MAX];     // hist, then running rank
    __shared__ int base_s[NBUCKET_MAX];
    const int tid = threadIdx.x;
    const int blk0 = blockIdx.x * EPB;
    const int nloc = min(EPB, E - blk0);

    for (int i = tid; i < NBUCKET_MAX; i += 256) cnt[i] = 0;
    __syncthreads();

    for (int i = tid; i < nloc; i += 256) {
        int r = row[blk0 + i];
        rows_s[i] = r;
        atomicAdd(&cnt[r >> 8], 1);
    }
    __syncthreads();

    for (int b = tid; b < NBUCKET_MAX; b += 256) {
        int c = cnt[b];
        base_s[b] = (c > 0) ? atomicAdd(&bcursor[b], c) : 0;
        cnt[b] = 0;  // reuse as running rank within this block's run
    }
    __syncthreads();

    for (int i = tid; i < nloc; i += 256) {
        int r = rows_s[i];
        int b = r >> 8;
        int lr = atomicAdd(&cnt[b], 1);          // LDS atomic
        int pos = base_s[b] + lr;
        int c = col[blk0 + i];
        float v = val[blk0 + i];
        // pack: col in bits 0..16 (M < 131072), row_local in bits 17..24
        bpair[pos] = make_int2(c | ((r & 255) << 17), __float_as_int(v));
    }
}

// Phase B: one block per 256-node bucket. LDS cursors = global CSR offsets.
// Reads bucket-grouped pairs coalesced, scatters CSR-sorted pairs within the
// bucket's contiguous region (single block/XCD -> full-line evictions).
__global__ __launch_bounds__(256) void local_sort_kernel(
        const int2* __restrict__ bpair, const int* __restrict__ offsets,
        int2* __restrict__ spair, int M) {
    __shared__ int lcur[256];
    const int b = blockIdx.x;
    const int node0 = b * 256;
    const int nnodes = min(256, M - node0);
    const int tid = threadIdx.x;
    if (tid < nnodes) lcur[tid] = offsets[node0 + tid];
    __syncthreads();
    const int beg = offsets[node0];
    const int end = offsets[node0 + nnodes];
    for (int i = beg + tid; i < end; i += 256) {
        int2 pk = bpair[i];
        int rl = (pk.x >> 17) & 255;
        int pos = atomicAdd(&lcur[rl], 1);       // LDS atomic
        spair[pos] = make_int2(pk.x & 0x1FFFF, pk.y);
    }
}

// ---------------- Conversions ----------------

// W (fp32 [k][n]) -> Wt (bf16 [n][k])
__global__ __launch_bounds__(256) void convert_wt_kernel(const float* __restrict__ W,
                                                         unsigned short* __restrict__ Wt) {
    int i = blockIdx.x * 256 + threadIdx.x;   // i = n*256 + k
    int n = i >> 8, k = i & 255;
    Wt[i] = f32_to_bf16(W[k * 256 + n]);
}

// ---------------- MFMA GEMM: XWb = X @ W  (fp32 in -> bf16 staged, bf16 out) ----------------
// BM=128, BN=128, BK=32. 256 threads = 4 waves in 2x2; each wave: 4x4 grid of 16x16 tiles.
// LDS rows padded to 40 bf16 (80B) -> 2-way bank aliasing (free).

__global__ __launch_bounds__(256) void gemm_mfma_kernel(const float* __restrict__ X,
                                                        const unsigned short* __restrict__ Wt,
                                                        unsigned short* __restrict__ XWb, int M) {
    __shared__ unsigned short As[128 * 40];  // [m][k] padded
    __shared__ unsigned short Bs[128 * 40];  // [n][k] padded

    const int tid = threadIdx.x;
    const int wave = tid >> 6, lane = tid & 63;
    const int quad = lane >> 4, r = lane & 15;
    const int wm = (wave & 1) * 64, wn = (wave >> 1) * 64;
    const int m0 = blockIdx.x * 128;
    const int n0 = blockIdx.y * 128;

    const int srow = tid >> 2;        // 0..63, staging row
    const int sseg = tid & 3;         // 16B (8-elem) segment within 32-k row

    f32x4 acc[4][4] = {};

    for (int k0 = 0; k0 < D; k0 += 32) {
        // stage A: 128 rows x 32 k; fp32 load + bf16 round fused
        #pragma unroll
        for (int h = 0; h < 2; ++h) {
            int row = srow + h * 64;
            int gm = m0 + row;
            ushort4 lo = make_ushort4(0, 0, 0, 0), hi = make_ushort4(0, 0, 0, 0);
            if (gm < M) {
                const float* src = X + (size_t)gm * D + k0 + sseg * 8;
                float4 f0 = *(const float4*)(src);
                float4 f1 = *(const float4*)(src + 4);
                lo.x = f32_to_bf16(f0.x); lo.y = f32_to_bf16(f0.y);
                lo.z = f32_to_bf16(f0.z); lo.w = f32_to_bf16(f0.w);
                hi.x = f32_to_bf16(f1.x); hi.y = f32_to_bf16(f1.y);
                hi.z = f32_to_bf16(f1.z); hi.w = f32_to_bf16(f1.w);
            }
            *(ushort4*)(&As[row * 40 + sseg * 8]) = lo;
            *(ushort4*)(&As[row * 40 + sseg * 8 + 4]) = hi;
        }
        // stage B: 128 n-rows x 32 k from Wt (already bf16)
        #pragma unroll
        for (int h = 0; h < 2; ++h) {
            int row = srow + h * 64;
            uint4 v = *(const uint4*)(Wt + (size_t)(n0 + row) * D + k0 + sseg * 8);
            *(uint4*)(&Bs[row * 40 + sseg * 8]) = v;
        }
        __syncthreads();

        bf16x8 a[4], b[4];
        #pragma unroll
        for (int mt = 0; mt < 4; ++mt)
            a[mt] = *(const bf16x8*)(&As[(wm + mt * 16 + r) * 40 + quad * 8]);
        #pragma unroll
        for (int nt = 0; nt < 4; ++nt)
            b[nt] = *(const bf16x8*)(&Bs[(wn + nt * 16 + r) * 40 + quad * 8]);
        #pragma unroll
        for (int mt = 0; mt < 4; ++mt)
            #pragma unroll
            for (int nt = 0; nt < 4; ++nt)
                acc[mt][nt] = __builtin_amdgcn_mfma_f32_16x16x32_bf16(a[mt], b[nt], acc[mt][nt], 0, 0, 0);
        __syncthreads();
    }

    // epilogue: C[row=quad*4+reg][col=lane&15] per 16x16 tile
    #pragma unroll
    for (int mt = 0; mt < 4; ++mt) {
        #pragma unroll
        for (int reg = 0; reg < 4; ++reg) {
            int gm = m0 + wm + mt * 16 + quad * 4 + reg;
            if (gm < M) {
                #pragma unroll
                for (int nt = 0; nt < 4; ++nt) {
                    int gn = n0 + wn + nt * 16 + r;
                    XWb[(size_t)gm * D + gn] = f32_to_bf16(acc[mt][nt][reg]);
                }
            }
        }
    }
}

// ---------------- Gather: out[node] = bias + sum_e val_e * XWb[col_e] ----------------
// One wave per node; lane owns 4 bf16 dims (8B load per edge). Unroll-4 for MLP.

__global__ __launch_bounds__(256) void gather_kernel(const unsigned short* __restrict__ XWb,
                                                     const int* __restrict__ offsets,
                                                     const int2* __restrict__ spair,
                                                     const float* __restrict__ bias,
                                                     float* __restrict__ out, int M) {
    int node = (int)((blockIdx.x * (size_t)blockDim.x + threadIdx.x) >> 6);
    int lane = threadIdx.x & 63;
    if (node >= M) return;
    int beg = offsets[node], end = offsets[node + 1];
    const unsigned short* base = XWb + lane * 4;
    float4 acc = make_float4(0.f, 0.f, 0.f, 0.f);
    int e = beg;
    for (; e + 3 < end; e += 4) {
        int2 p0 = spair[e];
        int2 p1 = spair[e + 1];
        int2 p2 = spair[e + 2];
        int2 p3 = spair[e + 3];
        ushort4 x0 = *(const ushort4*)(base + (size_t)p0.x * D);
        ushort4 x1 = *(const ushort4*)(base + (size_t)p1.x * D);
        ushort4 x2 = *(const ushort4*)(base + (size_t)p2.x * D);
        ushort4 x3 = *(const ushort4*)(base + (size_t)p3.x * D);
        float v0 = __int_as_float(p0.y), v1 = __int_as_float(p1.y);
        float v2 = __int_as_float(p2.y), v3 = __int_as_float(p3.y);
        acc.x += v0 * bf16_to_f32(x0.x); acc.y += v0 * bf16_to_f32(x0.y);
        acc.z += v0 * bf16_to_f32(x0.z); acc.w += v0 * bf16_to_f32(x0.w);
        acc.x += v1 * bf16_to_f32(x1.x); acc.y += v1 * bf16_to_f32(x1.y);
        acc.z += v1 * bf16_to_f32(x1.z); acc.w += v1 * bf16_to_f32(x1.w);
        acc.x += v2 * bf16_to_f32(x2.x); acc.y += v2 * bf16_to_f32(x2.y);
        acc.z += v2 * bf16_to_f32(x2.z); acc.w += v2 * bf16_to_f32(x2.w);
        acc.x += v3 * bf16_to_f32(x3.x); acc.y += v3 * bf16_to_f32(x3.y);
        acc.z += v3 * bf16_to_f32(x3.z); acc.w += v3 * bf16_to_f32(x3.w);
    }
    for (; e < end; ++e) {
        int2 p = spair[e];
        float v = __int_as_float(p.y);
        ushort4 x = *(const ushort4*)(base + (size_t)p.x * D);
        acc.x += v * bf16_to_f32(x.x); acc.y += v * bf16_to_f32(x.y);
        acc.z += v * bf16_to_f32(x.z); acc.w += v * bf16_to_f32(x.w);
    }
    float4 b = *(const float4*)(bias + lane * 4);
    acc.x += b.x; acc.y += b.y; acc.z += b.z; acc.w += b.w;
    *(float4*)(out + (size_t)node * D + lane * 4) = acc;
}

extern "C" void kernel_launch(void* const* d_in, const int* in_sizes, int n_in,
                              void* d_out, int out_size, void* d_ws, size_t ws_size,
                              hipStream_t stream) {
    const float* X    = (const float*)d_in[0];
    const int*   erow = (const int*)d_in[1];
    const int*   ecol = (const int*)d_in[2];
    const float* eval = (const float*)d_in[3];
    const float* W    = (const float*)d_in[4];
    const float* bias = (const float*)d_in[5];
    float* out = (float*)d_out;

    const int M = in_sizes[0] / D;   // 100000
    const int E = in_sizes[1];       // 1600000
    const int NB = (M + 255) / 256;  // 391 (== bucket count)

    // workspace carve (~78 MB)
    char* p = (char*)d_ws;
    unsigned short* XWb = (unsigned short*)p; p += (size_t)M * D * sizeof(unsigned short);
    unsigned short* Wt  = (unsigned short*)p; p += (size_t)D * D * sizeof(unsigned short);
    int* counts = (int*)p;      p += (size_t)M * sizeof(int);
    int* offsets = (int*)p;     p += (size_t)(M + 1) * sizeof(int);
    int* bcursor = (int*)p;     p += (size_t)NBUCKET_MAX * sizeof(int);
    int* partials = (int*)p;    p += (size_t)NB * sizeof(int);
    p = (char*)(((uintptr_t)p + 15) & ~(uintptr_t)15);
    int2* bpair = (int2*)p;     p += (size_t)E * sizeof(int2);
    int2* spair = (int2*)p;     p += (size_t)E * sizeof(int2);

    hipMemsetAsync(counts, 0, (size_t)M * sizeof(int), stream);
    hist_kernel<<<(E + 255) / 256, 256, 0, stream>>>(erow, counts, E);
    block_sums_kernel<<<NB, 256, 0, stream>>>(counts, partials, M);
    scan_partials_kernel<<<1, 256, 0, stream>>>(partials, NB);
    scan_local_kernel<<<NB, 256, 0, stream>>>(counts, partials, offsets, bcursor, M);
    binned_scatter_kernel<<<(E + EPB - 1) / EPB, 256, 0, stream>>>(erow, ecol, eval, bcursor, bpair, E);
    local_sort_kernel<<<NB, 256, 0, stream>>>(bpair, offsets, spair, M);

    convert_wt_kernel<<<(D * D) / 256, 256, 0, stream>>>(W, Wt);

    dim3 ggrid((M + 127) / 128, D / 128);
    gemm_mfma_kernel<<<ggrid, 256, 0, stream>>>(X, Wt, XWb, M);

    gather_kernel<<<(int)(((size_t)M * 64 + 255) / 256), 256, 0, stream>>>(
        XWb, offsets, spair, bias, out, M);
}

// Round 3
// 399.273 us; speedup vs baseline: 1.3287x; 1.1761x over previous
//
#include <hip/hip_runtime.h>
#include <hip/hip_bf16.h>
#include <stdint.h>

// out = A_sparse @ (X @ W) + b
// CSR build: bucket_hist (bucket-level only) -> tiny scan -> binned_scatter ->
//            local_sort (per-node offsets computed in-LDS, then in-bucket sort).
// GEMM: XWb = X @ W, MFMA 16x16x32 bf16, BM=128 BN=256 (X read exactly once),
//       fp32->bf16 fused into A-staging, 512 threads / 8 waves (2x4).
// Gather: one wave per node, 8B/lane row reads, unroll-4, nontemporal out store.

#define D 256             // D_IN == D_OUT == 256
#define EPB 4096          // edges per bucketing block
#define NBUCKET_MAX 512   // supports M <= 131072
#define CPAD 16           // bucket counter padding: one counter per 64B line

typedef __attribute__((ext_vector_type(8))) short bf16x8;
typedef __attribute__((ext_vector_type(4))) float f32x4;

__device__ __forceinline__ unsigned short f32_to_bf16(float f) {
    union { float f; unsigned int u; } x; x.f = f;
    unsigned int u = x.u;
    u += 0x7fffu + ((u >> 16) & 1u);   // round-to-nearest-even
    return (unsigned short)(u >> 16);
}
__device__ __forceinline__ float bf16_to_f32(unsigned short h) {
    union { unsigned int u; float f; } x; x.u = ((unsigned int)h) << 16;
    return x.f;
}

// ---------------- Bucket-level histogram (LDS hist, padded global adds) ----------------

__global__ __launch_bounds__(256) void bucket_hist_kernel(const int* __restrict__ row,
                                                          int* __restrict__ bcount, int E) {
    __shared__ int h[NBUCKET_MAX];
    const int tid = threadIdx.x;
    for (int i = tid; i < NBUCKET_MAX; i += 256) h[i] = 0;
    __syncthreads();
    const int blk0 = blockIdx.x * EPB;
    const int nloc = min(EPB, E - blk0);
    for (int i = tid; i < nloc; i += 256) atomicAdd(&h[row[blk0 + i] >> 8], 1);
    __syncthreads();
    for (int b = tid; b < NBUCKET_MAX; b += 256) {
        int c = h[b];
        if (c) atomicAdd(&bcount[b * CPAD], c);
    }
}

// Single-block exclusive scan over NB bucket counts (NB <= 512).
// Writes bucket_off[b] (compact), bcursor[b*CPAD], bucket_off[NB]=E, offsets[M]=E.
__global__ void scan_buckets_kernel(const int* __restrict__ bcount, int* __restrict__ bucket_off,
                                    int* __restrict__ bcursor, int* __restrict__ offsets,
                                    int NB, int M) {
    __shared__ int buf[256];
    __shared__ int carry_s;
    if (threadIdx.x == 0) carry_s = 0;
    __syncthreads();
    for (int base = 0; base < NB; base += 256) {
        int i = base + threadIdx.x;
        int v = (i < NB) ? bcount[i * CPAD] : 0;
        buf[threadIdx.x] = v;
        __syncthreads();
        #pragma unroll
        for (int off = 1; off < 256; off <<= 1) {
            int t = (threadIdx.x >= off) ? buf[threadIdx.x - off] : 0;
            __syncthreads();
            buf[threadIdx.x] += t;
            __syncthreads();
        }
        int excl = carry_s + buf[threadIdx.x] - v;
        if (i < NB) { bucket_off[i] = excl; bcursor[i * CPAD] = excl; }
        __syncthreads();
        if (threadIdx.x == 0) carry_s += buf[255];
        __syncthreads();
    }
    if (threadIdx.x == 0) { bucket_off[NB] = carry_s; offsets[M] = carry_s; }
}

// ---------------- Two-phase multisplit ----------------
// Phase A: bucket edges by row>>8; block-private contiguous runs -> full-line writes.

__global__ __launch_bounds__(256) void binned_scatter_kernel(
        const int* __restrict__ row, const int* __restrict__ col,
        const float* __restrict__ val, int* __restrict__ bcursor,
        int2* __restrict__ bpair, int E) {
    __shared__ int rows_s[EPB];          // 16 KB
    __shared__ int cnt[NBUCKET_MAX];
    __shared__ int base_s[NBUCKET_MAX];
    const int tid = threadIdx.x;
    const int blk0 = blockIdx.x * EPB;
    const int nloc = min(EPB, E - blk0);

    for (int i = tid; i < NBUCKET_MAX; i += 256) cnt[i] = 0;
    __syncthreads();

    for (int i = tid; i < nloc; i += 256) {
        int r = row[blk0 + i];
        rows_s[i] = r;
        atomicAdd(&cnt[r >> 8], 1);
    }
    __syncthreads();

    for (int b = tid; b < NBUCKET_MAX; b += 256) {
        int c = cnt[b];
        base_s[b] = (c > 0) ? atomicAdd(&bcursor[b * CPAD], c) : 0;
        cnt[b] = 0;  // reuse as running rank
    }
    __syncthreads();

    for (int i = tid; i < nloc; i += 256) {
        int r = rows_s[i];
        int b = r >> 8;
        int lr = atomicAdd(&cnt[b], 1);          // LDS atomic
        int pos = base_s[b] + lr;
        // pack: col in bits 0..16 (M < 131072), row_local in bits 17..24
        bpair[pos] = make_int2(col[blk0 + i] | ((r & 255) << 17), __float_as_int(val[blk0 + i]));
    }
}

// Phase B: one block per 256-node bucket. Computes per-node CSR offsets in-LDS
// (hist + scan), writes offsets[], then scatters sorted pairs within the
// bucket's contiguous region.
__global__ __launch_bounds__(256) void local_sort_kernel(
        const int2* __restrict__ bpair, const int* __restrict__ bucket_off,
        int* __restrict__ offsets, int2* __restrict__ spair, int M) {
    __shared__ int hist[256];
    __shared__ int buf[256];
    __shared__ int lcur[256];
    const int b = blockIdx.x;
    const int tid = threadIdx.x;
    const int node0 = b << 8;
    const int nn = min(256, M - node0);
    const int beg = bucket_off[b], end = bucket_off[b + 1];

    hist[tid] = 0;
    __syncthreads();
    for (int i = beg + tid; i < end; i += 256)
        atomicAdd(&hist[(bpair[i].x >> 17) & 255], 1);
    __syncthreads();

    int v = hist[tid];
    buf[tid] = v;
    __syncthreads();
    #pragma unroll
    for (int off = 1; off < 256; off <<= 1) {
        int t = (tid >= off) ? buf[tid - off] : 0;
        __syncthreads();
        buf[tid] += t;
        __syncthreads();
    }
    int o = beg + buf[tid] - v;   // exclusive
    if (tid < nn) offsets[node0 + tid] = o;
    lcur[tid] = o;
    __syncthreads();

    for (int i = beg + tid; i < end; i += 256) {
        int2 pk = bpair[i];
        int pos = atomicAdd(&lcur[(pk.x >> 17) & 255], 1);   // LDS atomic
        spair[pos] = make_int2(pk.x & 0x1FFFF, pk.y);
    }
}

// ---------------- Conversions ----------------

// W (fp32 [k][n]) -> Wt (bf16 [n][k])
__global__ __launch_bounds__(256) void convert_wt_kernel(const float* __restrict__ W,
                                                         unsigned short* __restrict__ Wt) {
    int i = blockIdx.x * 256 + threadIdx.x;   // i = n*256 + k
    int n = i >> 8, k = i & 255;
    Wt[i] = f32_to_bf16(W[k * 256 + n]);
}

// ---------------- MFMA GEMM: XWb = X @ W ----------------
// BM=128, BN=256, BK=32. 512 threads = 8 waves (2x4); wave tile 64x64 = 4x4 MFMA tiles.
// X read exactly once (nontemporal), fp32->bf16 round fused into A-staging.
// LDS rows padded to 40 bf16 (80B) -> 2-way bank aliasing (free).

__global__ __launch_bounds__(512) void gemm_mfma_kernel(const float* __restrict__ X,
                                                        const unsigned short* __restrict__ Wt,
                                                        unsigned short* __restrict__ XWb, int M) {
    __shared__ unsigned short As[128 * 40];  // [m][k] padded
    __shared__ unsigned short Bs[256 * 40];  // [n][k] padded

    const int tid = threadIdx.x;
    const int wave = tid >> 6, lane = tid & 63;
    const int quad = lane >> 4, r = lane & 15;
    const int wr = wave >> 2, wc = wave & 3;   // 2 x 4 wave grid
    const int m0 = blockIdx.x * 128;

    const int srow = tid >> 2;        // 0..127
    const int sseg = tid & 3;         // 8-elem segment within 32-k row

    f32x4 acc[4][4] = {};

    for (int k0 = 0; k0 < D; k0 += 32) {
        // stage A: 128 rows x 32 k; fp32 nt-load + bf16 round
        {
            int gm = m0 + srow;
            ushort4 lo = make_ushort4(0, 0, 0, 0), hi = make_ushort4(0, 0, 0, 0);
            if (gm < M) {
                const f32x4* src = (const f32x4*)(X + (size_t)gm * D + k0 + sseg * 8);
                f32x4 f0 = __builtin_nontemporal_load(src);
                f32x4 f1 = __builtin_nontemporal_load(src + 1);
                lo.x = f32_to_bf16(f0[0]); lo.y = f32_to_bf16(f0[1]);
                lo.z = f32_to_bf16(f0[2]); lo.w = f32_to_bf16(f0[3]);
                hi.x = f32_to_bf16(f1[0]); hi.y = f32_to_bf16(f1[1]);
                hi.z = f32_to_bf16(f1[2]); hi.w = f32_to_bf16(f1[3]);
            }
            *(ushort4*)(&As[srow * 40 + sseg * 8]) = lo;
            *(ushort4*)(&As[srow * 40 + sseg * 8 + 4]) = hi;
        }
        // stage B: 256 n-rows x 32 k from Wt
        #pragma unroll
        for (int h = 0; h < 2; ++h) {
            int rowB = srow + h * 128;
            uint4 w = *(const uint4*)(Wt + (size_t)rowB * D + k0 + sseg * 8);
            *(uint4*)(&Bs[rowB * 40 + sseg * 8]) = w;
        }
        __syncthreads();

        bf16x8 a[4], bb[4];
        #pragma unroll
        for (int mt = 0; mt < 4; ++mt)
            a[mt] = *(const bf16x8*)(&As[(wr * 64 + mt * 16 + r) * 40 + quad * 8]);
        #pragma unroll
        for (int nt = 0; nt < 4; ++nt)
            bb[nt] = *(const bf16x8*)(&Bs[(wc * 64 + nt * 16 + r) * 40 + quad * 8]);
        #pragma unroll
        for (int mt = 0; mt < 4; ++mt)
            #pragma unroll
            for (int nt = 0; nt < 4; ++nt)
                acc[mt][nt] = __builtin_amdgcn_mfma_f32_16x16x32_bf16(a[mt], bb[nt], acc[mt][nt], 0, 0, 0);
        __syncthreads();
    }

    // epilogue: C[row=quad*4+reg][col=lane&15] per 16x16 tile
    #pragma unroll
    for (int mt = 0; mt < 4; ++mt) {
        #pragma unroll
        for (int reg = 0; reg < 4; ++reg) {
            int gm = m0 + wr * 64 + mt * 16 + quad * 4 + reg;
            if (gm < M) {
                #pragma unroll
                for (int nt = 0; nt < 4; ++nt) {
                    int gn = wc * 64 + nt * 16 + r;
                    XWb[(size_t)gm * D + gn] = f32_to_bf16(acc[mt][nt][reg]);
                }
            }
        }
    }
}

// ---------------- Gather: out[node] = bias + sum_e val_e * XWb[col_e] ----------------
// One wave per node; lane owns 4 bf16 dims (8B load per edge). Unroll-4 for MLP.
// Nontemporal out store: don't let the 100MB write stream evict XWb from L2.

__global__ __launch_bounds__(256) void gather_kernel(const unsigned short* __restrict__ XWb,
                                                     const int* __restrict__ offsets,
                                                     const int2* __restrict__ spair,
                                                     const float* __restrict__ bias,
                                                     float* __restrict__ out, int M) {
    int node = (int)((blockIdx.x * (size_t)blockDim.x + threadIdx.x) >> 6);
    int lane = threadIdx.x & 63;
    if (node >= M) return;
    int beg = offsets[node], end = offsets[node + 1];
    const unsigned short* base = XWb + lane * 4;
    float4 acc = make_float4(0.f, 0.f, 0.f, 0.f);
    int e = beg;
    for (; e + 3 < end; e += 4) {
        int2 p0 = spair[e];
        int2 p1 = spair[e + 1];
        int2 p2 = spair[e + 2];
        int2 p3 = spair[e + 3];
        ushort4 x0 = *(const ushort4*)(base + (size_t)p0.x * D);
        ushort4 x1 = *(const ushort4*)(base + (size_t)p1.x * D);
        ushort4 x2 = *(const ushort4*)(base + (size_t)p2.x * D);
        ushort4 x3 = *(const ushort4*)(base + (size_t)p3.x * D);
        float v0 = __int_as_float(p0.y), v1 = __int_as_float(p1.y);
        float v2 = __int_as_float(p2.y), v3 = __int_as_float(p3.y);
        acc.x += v0 * bf16_to_f32(x0.x); acc.y += v0 * bf16_to_f32(x0.y);
        acc.z += v0 * bf16_to_f32(x0.z); acc.w += v0 * bf16_to_f32(x0.w);
        acc.x += v1 * bf16_to_f32(x1.x); acc.y += v1 * bf16_to_f32(x1.y);
        acc.z += v1 * bf16_to_f32(x1.z); acc.w += v1 * bf16_to_f32(x1.w);
        acc.x += v2 * bf16_to_f32(x2.x); acc.y += v2 * bf16_to_f32(x2.y);
        acc.z += v2 * bf16_to_f32(x2.z); acc.w += v2 * bf16_to_f32(x2.w);
        acc.x += v3 * bf16_to_f32(x3.x); acc.y += v3 * bf16_to_f32(x3.y);
        acc.z += v3 * bf16_to_f32(x3.z); acc.w += v3 * bf16_to_f32(x3.w);
    }
    for (; e < end; ++e) {
        int2 p = spair[e];
        float v = __int_as_float(p.y);
        ushort4 x = *(const ushort4*)(base + (size_t)p.x * D);
        acc.x += v * bf16_to_f32(x.x); acc.y += v * bf16_to_f32(x.y);
        acc.z += v * bf16_to_f32(x.z); acc.w += v * bf16_to_f32(x.w);
    }
    float4 b = *(const float4*)(bias + lane * 4);
    acc.x += b.x; acc.y += b.y; acc.z += b.z; acc.w += b.w;
    __builtin_nontemporal_store(*(f32x4*)&acc, (f32x4*)(out + (size_t)node * D + lane * 4));
}

extern "C" void kernel_launch(void* const* d_in, const int* in_sizes, int n_in,
                              void* d_out, int out_size, void* d_ws, size_t ws_size,
                              hipStream_t stream) {
    const float* X    = (const float*)d_in[0];
    const int*   erow = (const int*)d_in[1];
    const int*   ecol = (const int*)d_in[2];
    const float* eval = (const float*)d_in[3];
    const float* W    = (const float*)d_in[4];
    const float* bias = (const float*)d_in[5];
    float* out = (float*)d_out;

    const int M = in_sizes[0] / D;   // 100000
    const int E = in_sizes[1];       // 1600000
    const int NB = (M + 255) / 256;  // 391 buckets

    // workspace carve (~78 MB)
    char* p = (char*)d_ws;
    unsigned short* XWb = (unsigned short*)p; p += (size_t)M * D * sizeof(unsigned short);
    unsigned short* Wt  = (unsigned short*)p; p += (size_t)D * D * sizeof(unsigned short);
    int* bcount = (int*)p;      p += (size_t)NBUCKET_MAX * CPAD * sizeof(int);
    int* bcursor = (int*)p;     p += (size_t)NBUCKET_MAX * CPAD * sizeof(int);
    int* bucket_off = (int*)p;  p += (size_t)(NB + 1) * sizeof(int);
    int* offsets = (int*)p;     p += (size_t)(M + 1) * sizeof(int);
    p = (char*)(((uintptr_t)p + 15) & ~(uintptr_t)15);
    int2* bpair = (int2*)p;     p += (size_t)E * sizeof(int2);
    int2* spair = (int2*)p;     p += (size_t)E * sizeof(int2);

    hipMemsetAsync(bcount, 0, (size_t)NBUCKET_MAX * CPAD * sizeof(int), stream);
    bucket_hist_kernel<<<(E + EPB - 1) / EPB, 256, 0, stream>>>(erow, bcount, E);
    scan_buckets_kernel<<<1, 256, 0, stream>>>(bcount, bucket_off, bcursor, offsets, NB, M);
    binned_scatter_kernel<<<(E + EPB - 1) / EPB, 256, 0, stream>>>(erow, ecol, eval, bcursor, bpair, E);
    local_sort_kernel<<<NB, 256, 0, stream>>>(bpair, bucket_off, offsets, spair, M);

    convert_wt_kernel<<<(D * D) / 256, 256, 0, stream>>>(W, Wt);

    gemm_mfma_kernel<<<(M + 127) / 128, 512, 0, stream>>>(X, Wt, XWb, M);

    gather_kernel<<<(int)(((size_t)M * 64 + 255) / 256), 256, 0, stream>>>(
        XWb, offsets, spair, bias, out, M);
}